// Round 1
// baseline (967.075 us; speedup 1.0000x reference)
//
#include <hip/hip_runtime.h>
#include <math.h>

#define EPSF 1e-8f

constexpr int Wd = 512;
constexpr int Hd = 512;
constexpr int Cd = 128;
constexpr int Bd = 2;
constexpr int HW = Hd * Wd;      // 262144 = 2^18
constexpr int NPLANE = Bd * Cd;  // 256
constexpr int NTHREADS = 1024;
constexpr int NWAVES = NTHREADS / 64;  // 16

typedef float f32x4 __attribute__((ext_vector_type(4)));

__device__ __forceinline__ void store_nt(float* p, float4 v) {
    __builtin_nontemporal_store(*(f32x4*)&v, (f32x4*)p);
}

// One block per (b,c) plane. Phase 1: stats (row/col/instance) with a single
// coalesced read of the plane; fold gamma/beta/mean/invstd into per-row,
// per-col, per-instance affine (a,b) pairs in LDS. Phase 2: re-read plane,
// one fma per output element, 3x float4 streaming stores.
__global__ __launch_bounds__(NTHREADS, 1)
void ircn_fused(const float* __restrict__ x,
                const float* __restrict__ gRow, const float* __restrict__ bRow,
                const float* __restrict__ gCol, const float* __restrict__ bCol,
                const float* __restrict__ gIns, const float* __restrict__ bIns,
                float* __restrict__ out)
{
    __shared__ float sPartS[NWAVES][Wd];   // 32 KB col partial sums
    __shared__ float sPartQ[NWAVES][Wd];   // 32 KB col partial sumsq
    __shared__ float rowA[Hd], rowB[Hd];   // 4 KB
    __shared__ float colA[Wd], colB[Wd];   // 4 KB
    __shared__ float sWaveS[NWAVES], sWaveQ[NWAVES];
    __shared__ float sInsA, sInsB;

    const int plane = blockIdx.x;            // 0..255
    const int tid   = threadIdx.x;
    const int wave  = tid >> 6;
    const int lane  = tid & 63;
    const int c     = plane & (Cd - 1);

    const float gr = gRow[c], br = bRow[c];
    const float gc = gCol[c], bc = bCol[c];
    const float gi = gIns[c], bi = bIns[c];

    const float* __restrict__ px = x + (size_t)plane * HW;

    // ---------------- Phase 1: stats ----------------
    // lane owns columns 4*lane..4*lane+3 and 256+4*lane..256+4*lane+3
    float colS[8] = {0,0,0,0,0,0,0,0};
    float colQ[8] = {0,0,0,0,0,0,0,0};

    for (int r = wave; r < Hd; r += NWAVES) {
        const float4 a = *(const float4*)(px + (size_t)r * Wd + 4 * lane);
        const float4 d = *(const float4*)(px + (size_t)r * Wd + 256 + 4 * lane);
        float ax = a.x * a.x, ay = a.y * a.y, az = a.z * a.z, aw = a.w * a.w;
        float dx = d.x * d.x, dy = d.y * d.y, dz = d.z * d.z, dw = d.w * d.w;
        colS[0] += a.x; colS[1] += a.y; colS[2] += a.z; colS[3] += a.w;
        colS[4] += d.x; colS[5] += d.y; colS[6] += d.z; colS[7] += d.w;
        colQ[0] += ax;  colQ[1] += ay;  colQ[2] += az;  colQ[3] += aw;
        colQ[4] += dx;  colQ[5] += dy;  colQ[6] += dz;  colQ[7] += dw;

        float rs = (a.x + a.y) + (a.z + a.w) + (d.x + d.y) + (d.z + d.w);
        float rq = (ax + ay) + (az + aw) + (dx + dy) + (dz + dw);
        #pragma unroll
        for (int off = 32; off > 0; off >>= 1) {
            rs += __shfl_down(rs, off, 64);
            rq += __shfl_down(rq, off, 64);
        }
        if (lane == 0) {
            float m = rs * (1.0f / Wd);
            float v = fmaxf(rq * (1.0f / Wd) - m * m, 0.0f);
            float inv = 1.0f / (sqrtf(v + EPSF) + EPSF);
            float aa = gr * inv;
            rowA[r] = aa;
            rowB[r] = br - aa * m;
        }
    }

    // dump column partials to LDS (once per block, conflicts negligible)
    #pragma unroll
    for (int k = 0; k < 4; k++) {
        sPartS[wave][4 * lane + k]       = colS[k];
        sPartQ[wave][4 * lane + k]       = colQ[k];
        sPartS[wave][256 + 4 * lane + k] = colS[4 + k];
        sPartQ[wave][256 + 4 * lane + k] = colQ[4 + k];
    }
    __syncthreads();

    float insS = 0.0f, insQ = 0.0f;
    if (tid < Wd) {
        float s = 0.0f, q = 0.0f;
        #pragma unroll
        for (int wv = 0; wv < NWAVES; wv++) { s += sPartS[wv][tid]; q += sPartQ[wv][tid]; }
        float m = s * (1.0f / Hd);
        float v = fmaxf(q * (1.0f / Hd) - m * m, 0.0f);
        float inv = 1.0f / (sqrtf(v + EPSF) + EPSF);
        float aa = gc * inv;
        colA[tid] = aa;
        colB[tid] = bc - aa * m;
        insS = s; insQ = q;
    }
    // block-reduce instance sums (tid >= 512 contribute 0)
    #pragma unroll
    for (int off = 32; off > 0; off >>= 1) {
        insS += __shfl_down(insS, off, 64);
        insQ += __shfl_down(insQ, off, 64);
    }
    if (lane == 0) { sWaveS[wave] = insS; sWaveQ[wave] = insQ; }
    __syncthreads();
    if (tid == 0) {
        float S = 0.0f, Q = 0.0f;
        #pragma unroll
        for (int wv = 0; wv < NWAVES; wv++) { S += sWaveS[wv]; Q += sWaveQ[wv]; }
        float m = S * (1.0f / HW);
        float v = fmaxf(Q * (1.0f / HW) - m * m, 0.0f);
        float inv = 1.0f / (sqrtf(v + EPSF) + EPSF);
        float aa = gi * inv;
        sInsA = aa;
        sInsB = bi - aa * m;
    }
    __syncthreads();

    // ---------------- Phase 2: apply ----------------
    const float aI = sInsA, bI = sInsB;
    const size_t baseIns = ((size_t)((plane >> 7) * 3 * Cd + c)) << 18;
    float* __restrict__ outIns = out + baseIns;
    float* __restrict__ outRow = out + baseIns + ((size_t)Cd << 18);
    float* __restrict__ outCol = out + baseIns + ((size_t)(2 * Cd) << 18);

    constexpr int NITER = HW / 4 / NTHREADS;  // 64
    #pragma unroll 2
    for (int it = 0; it < NITER; ++it) {
        const int i4 = it * NTHREADS + tid;
        const int h  = i4 >> 7;          // 128 float4 per row
        const int w4 = i4 & 127;
        const size_t off = (size_t)i4 * 4;

        const float4 xv = *(const float4*)(px + off);
        const float aR = rowA[h], bR = rowB[h];
        const float4 aC = *(const float4*)(colA + 4 * w4);
        const float4 bC = *(const float4*)(colB + 4 * w4);

        float4 oI, oR, oC;
        oI.x = fmaf(aI, xv.x, bI);   oI.y = fmaf(aI, xv.y, bI);
        oI.z = fmaf(aI, xv.z, bI);   oI.w = fmaf(aI, xv.w, bI);
        oR.x = fmaf(aR, xv.x, bR);   oR.y = fmaf(aR, xv.y, bR);
        oR.z = fmaf(aR, xv.z, bR);   oR.w = fmaf(aR, xv.w, bR);
        oC.x = fmaf(aC.x, xv.x, bC.x); oC.y = fmaf(aC.y, xv.y, bC.y);
        oC.z = fmaf(aC.z, xv.z, bC.z); oC.w = fmaf(aC.w, xv.w, bC.w);

        store_nt(outIns + off, oI);
        store_nt(outRow + off, oR);
        store_nt(outCol + off, oC);
    }
}

extern "C" void kernel_launch(void* const* d_in, const int* in_sizes, int n_in,
                              void* d_out, int out_size, void* d_ws, size_t ws_size,
                              hipStream_t stream) {
    const float* x    = (const float*)d_in[0];
    const float* gRow = (const float*)d_in[1];
    const float* bRow = (const float*)d_in[2];
    const float* gCol = (const float*)d_in[3];
    const float* bCol = (const float*)d_in[4];
    const float* gIns = (const float*)d_in[5];
    const float* bIns = (const float*)d_in[6];
    float* out = (float*)d_out;

    ircn_fused<<<NPLANE, NTHREADS, 0, stream>>>(x, gRow, bRow, gCol, bCol,
                                                gIns, bIns, out);
}